// Round 1
// 663.752 us; speedup vs baseline: 1.0282x; 1.0282x over previous
//
#include <hip/hip_runtime.h>
#include <hip/hip_bf16.h>

#define B_ 256
#define N_ 256
#define M_ 256
#define D_ 1024
#define RAD 128
#define BIGF 1e30f
#define LDK 40   // padded LDS row stride in shorts (80 B): bank group = (20*row+4*slot)%32
                 // -> both b128 frag reads and staging writes hit the 8-cycle minimum (conflict-free)

typedef short bf16x8 __attribute__((ext_vector_type(8)));
typedef float f32x4 __attribute__((ext_vector_type(4)));

__device__ __forceinline__ short f2bf(float f) {
    __hip_bfloat16 h = __float2bfloat16(f);
    return __builtin_bit_cast(short, h);
}

__device__ __forceinline__ void cvt4(const float4 v, short* s, float& n) {
    n += v.x * v.x + v.y * v.y + v.z * v.z + v.w * v.w;
    s[0] = f2bf(v.x); s[1] = f2bf(v.y); s[2] = f2bf(v.z); s[3] = f2bf(v.w);
}

// One K-step's worth of global data for one thread: 64 B of A-row + 64 B of B-row.
struct Pk { float4 a0, a1, a2, a3, b0, b1, b2, b3; };

__device__ __forceinline__ Pk loadpk(const float* ax, const float* by) {
    Pk p;
    p.a0 = *(const float4*)(ax + 0);
    p.a1 = *(const float4*)(ax + 4);
    p.a2 = *(const float4*)(ax + 8);
    p.a3 = *(const float4*)(ax + 12);
    p.b0 = *(const float4*)(by + 0);
    p.b1 = *(const float4*)(by + 4);
    p.b2 = *(const float4*)(by + 8);
    p.b3 = *(const float4*)(by + 12);
    return p;
}

// Phase 1: per-batch bf16 MFMA GEMM sim = X.Y^T with fused row-norm
// computation; epilogue writes dist = 1 - clamp(sim*rnx*rny, -1, 1).
// Grid: 256 batches x 4 tiles of 128x128. Block: 256 threads (4 waves),
// each wave owns a 64x64 subtile as 4x4 fragments of 16x16x32 bf16 MFMA.
// K-loop: software-pipelined (loads 1 step ahead, 8 float4 always in
// flight) + double-buffered LDS (1 barrier per K-step) + stride-40 pad.
__global__ __launch_bounds__(256) void gemm_dist_kernel(
        const float* __restrict__ X, const float* __restrict__ Y,
        float* __restrict__ dist) {
    const int bid = blockIdx.x;
    const int b  = bid >> 2;
    const int ti = (bid >> 1) & 1;
    const int tj = bid & 1;

    __shared__ alignas(16) short As[2][128][LDK];   // 20480 B
    __shared__ alignas(16) short Bs[2][128][LDK];   // 20480 B -> 40960 B total = 4 blocks/CU

    const int t    = threadIdx.x;
    const int row  = t >> 1;          // staged row 0..127 (A and B)
    const int kh   = (t & 1) << 4;    // k half: 0 or 16
    const int wave = t >> 6;
    const int lane = t & 63;
    const int wi   = (wave >> 1) << 6;
    const int wj   = (wave & 1) << 6;
    const int fq   = lane >> 4;       // quad 0..3
    const int fr   = lane & 15;

    const float* ax = X + (((size_t)b * N_ + ti * 128 + row) * D_) + kh;
    const float* by = Y + (((size_t)b * M_ + tj * 128 + row) * D_) + kh;

    f32x4 acc[4][4];
    const f32x4 zero = {0.f, 0.f, 0.f, 0.f};
#pragma unroll
    for (int r = 0; r < 4; ++r)
#pragma unroll
        for (int c = 0; c < 4; ++c) acc[r][c] = zero;

    float nA = 0.f, nB = 0.f;

    // Convert + stage one K-step into LDS buffer `buf`, then MFMA from it.
    // Single barrier per step: writes(buf) -> sync -> reads(buf); the next
    // step writes buf^1, and re-writes of buf are separated from the last
    // reads of buf by the intervening step's barrier (race-free).
    auto stage = [&](const Pk& p, int buf) {
        short sa[16], sb[16];
        cvt4(p.a0, sa + 0,  nA); cvt4(p.a1, sa + 4,  nA);
        cvt4(p.a2, sa + 8,  nA); cvt4(p.a3, sa + 12, nA);
        cvt4(p.b0, sb + 0,  nB); cvt4(p.b1, sb + 4,  nB);
        cvt4(p.b2, sb + 8,  nB); cvt4(p.b3, sb + 12, nB);

        *(bf16x8*)&As[buf][row][kh]     = *(bf16x8*)&sa[0];
        *(bf16x8*)&As[buf][row][kh + 8] = *(bf16x8*)&sa[8];
        *(bf16x8*)&Bs[buf][row][kh]     = *(bf16x8*)&sb[0];
        *(bf16x8*)&Bs[buf][row][kh + 8] = *(bf16x8*)&sb[8];
        __syncthreads();

        bf16x8 af[4], bfr[4];
#pragma unroll
        for (int r = 0; r < 4; ++r)
            af[r] = *(const bf16x8*)&As[buf][wi + r * 16 + fr][fq * 8];
#pragma unroll
        for (int c = 0; c < 4; ++c)
            bfr[c] = *(const bf16x8*)&Bs[buf][wj + c * 16 + fr][fq * 8];
#pragma unroll
        for (int r = 0; r < 4; ++r)
#pragma unroll
            for (int c = 0; c < 4; ++c)
                acc[r][c] = __builtin_amdgcn_mfma_f32_16x16x32_bf16(
                    af[r], bfr[c], acc[r][c], 0, 0, 0);
    };

    // Pipeline: always one K-step of global loads in flight behind the
    // step being converted/MFMA'd.
    Pk cur = loadpk(ax, by); ax += 32; by += 32;
    for (int kt = 0; kt < D_ / 32; kt += 2) {
        Pk nxt = loadpk(ax, by); ax += 32; by += 32;   // loads for kt+1 in flight
        stage(cur, 0);
        if (kt + 2 < D_ / 32) {                        // loads for kt+2 in flight
            cur = loadpk(ax, by); ax += 32; by += 32;
        }
        stage(nxt, 1);
    }

    // Row norms: thread t and t^1 jointly covered row t>>1 over all K.
    // Reduction scratch overlays the (now dead) LDS tile buffers.
    __syncthreads();   // last step's MFMA LDS reads complete before overlay
    float* scratch = (float*)&As[0][0][0];
    scratch[t]       = nA;   // redA[256]
    scratch[256 + t] = nB;   // redB[256]
    __syncthreads();
    if (t < 128) {
        float sA = scratch[2 * t] + scratch[2 * t + 1];
        float sB = scratch[256 + 2 * t] + scratch[256 + 2 * t + 1];
        scratch[512 + t] = 1.0f / fmaxf(sqrtf(sA), 1e-12f);   // rnx[128]
        scratch[640 + t] = 1.0f / fmaxf(sqrtf(sB), 1e-12f);   // rny[128]
    }
    __syncthreads();
    const float* rnx = scratch + 512;
    const float* rny = scratch + 640;

    // Epilogue: C/D layout col=lane&15, row=quad*4+reg (m89-verified).
    float* Dp = dist + (((size_t)b * N_ + ti * 128) * M_) + tj * 128;
#pragma unroll
    for (int r = 0; r < 4; ++r) {
#pragma unroll
        for (int c = 0; c < 4; ++c) {
            const int col = wj + c * 16 + fr;
            const float rc = rny[col];
#pragma unroll
            for (int g = 0; g < 4; ++g) {
                const int rw = wi + r * 16 + fq * 4 + g;
                float v = acc[r][c][g] * rnx[rw] * rc;
                v = fminf(1.0f, fmaxf(-1.0f, v));
                Dp[(size_t)rw * M_ + col] = 1.0f - v;
            }
        }
    }
}

// Phase 2: banded DTW, one wave per batch. Lane l owns columns 4l..4l+3.
// Row recurrence a[j] = min(bt[j], a[j-1]+st[j]) solved as a min-plus scan:
// within-lane fold of (s,t) pairs + 6-step shfl_up wave scan. No barriers.
__global__ __launch_bounds__(64) void dtw_kernel(
        const float* __restrict__ dist, float* __restrict__ out) {
    const int b = blockIdx.x;
    const int lane = threadIdx.x;
    const float* Db = dist + (size_t)b * N_ * M_;
    const int j0 = lane << 2;

    // ---- row 0: masked cumulative sum ----
    float4 d = *(const float4*)(Db + j0);
    float s0 = d.x, s1 = s0 + d.y, s2 = s1 + d.z, s3 = s2 + d.w;
    float tot = s3;
#pragma unroll
    for (int off = 1; off < 64; off <<= 1) {
        float o = __shfl_up(tot, off);
        if (lane >= off) tot += o;
    }
    float excl = __shfl_up(tot, 1);
    if (lane == 0) excl = 0.f;
    float prev[4];
    prev[0] = (j0 + 0 <= RAD) ? excl + s0 : BIGF;
    prev[1] = (j0 + 1 <= RAD) ? excl + s1 : BIGF;
    prev[2] = (j0 + 2 <= RAD) ? excl + s2 : BIGF;
    prev[3] = (j0 + 3 <= RAD) ? excl + s3 : BIGF;

    float4 dn = *(const float4*)(Db + M_ + j0);  // prefetch row 1

    for (int i = 1; i < N_; ++i) {
        d = dn;
        if (i + 1 < N_) dn = *(const float4*)(Db + (size_t)(i + 1) * M_ + j0);

        const float pm1 = __shfl_up(prev[3], 1);        // prev[j-1] at slot 0
        const float p00 = __shfl(prev[0], 0);
        const float d00 = __shfl(d.x, 0);
        const float a0 = (i <= RAD) ? p00 + d00 : BIGF;

        const float de[4] = {d.x, d.y, d.z, d.w};
        const float ps[4] = {pm1, prev[0], prev[1], prev[2]};

        // within-lane inclusive fold of (st, bt) pairs; element j==0 is the
        // monoid identity (0, +BIG)
        float S = 0.f, T = BIGF;
        float Se[4], Te[4];
#pragma unroll
        for (int e = 0; e < 4; ++e) {
            const int j = j0 + e;
            float st, bt;
            if (j == 0) {
                st = 0.f; bt = BIGF;
            } else {
                const bool in = (j >= i - RAD) && (j <= i + RAD);
                const float c = fminf(prev[e], ps[e]);
                bt = in ? c + de[e] : BIGF;
                st = in ? de[e] : BIGF;
            }
            T = fminf(bt, T + st);   // comb(p, x)
            S = S + st;
            Se[e] = S; Te[e] = T;
        }

        // wave inclusive scan of lane totals with comb(left, self)
        float iS = S, iT = T;
#pragma unroll
        for (int off = 1; off < 64; off <<= 1) {
            float oS = __shfl_up(iS, off);
            float oT = __shfl_up(iT, off);
            if (lane >= off) {
                iT = fminf(iT, oT + iS);
                iS = oS + iS;
            }
        }
        float eS = __shfl_up(iS, 1);
        float eT = __shfl_up(iT, 1);
        if (lane == 0) { eS = 0.f; eT = BIGF; }

#pragma unroll
        for (int e = 0; e < 4; ++e) {
            const float fS = eS + Se[e];
            const float fT = fminf(Te[e], eT + Se[e]);
            prev[e] = fminf(fT, a0 + fS);
        }
        if (lane == 0) prev[0] = a0;
    }

    if (lane == 63) out[b] = prev[3];
}

extern "C" void kernel_launch(void* const* d_in, const int* in_sizes, int n_in,
                              void* d_out, int out_size, void* d_ws, size_t ws_size,
                              hipStream_t stream) {
    const float* seq1 = (const float*)d_in[0];
    const float* seq2 = (const float*)d_in[1];
    float* out = (float*)d_out;
    float* dist = (float*)d_ws;   // 256*256*256*4 = 64 MiB scratch

    hipLaunchKernelGGL(gemm_dist_kernel, dim3(B_ * 4), dim3(256), 0, stream,
                       seq1, seq2, dist);
    hipLaunchKernelGGL(dtw_kernel, dim3(B_), dim3(64), 0, stream, dist, out);
}

// Round 2
// 641.041 us; speedup vs baseline: 1.0646x; 1.0354x over previous
//
#include <hip/hip_runtime.h>
#include <hip/hip_bf16.h>

#define B_ 256
#define N_ 256
#define M_ 256
#define D_ 1024
#define RAD 128
#define BIGF 1e30f

typedef short bf16x8 __attribute__((ext_vector_type(8)));
typedef float f32x4 __attribute__((ext_vector_type(4)));

__device__ __forceinline__ short f2bf(float f) {
    __hip_bfloat16 h = __float2bfloat16(f);
    return __builtin_bit_cast(short, h);
}

// global -> LDS direct, 16 B per lane. LDS dest is wave-uniform base + lane*16
// (m104/m108): destination stays LINEAR; all swizzling is done on the global
// source address and mirrored on the LDS read side (rule #21, m173/m201).
#define GLL16(g, l)                                                        \
    __builtin_amdgcn_global_load_lds(                                      \
        (const __attribute__((address_space(1))) void*)(g),                \
        (__attribute__((address_space(3))) void*)(l), 16, 0, 0)

// Phase 1: per-batch bf16 MFMA GEMM sim = X.Y^T with fused row-norms;
// epilogue writes dist = 1 - clamp(sim*rnx*rny, -1, 1).
// Grid: 256 batches x 4 tiles of 128x128 (XCD-swizzled). Block: 256 threads
// (4 waves), each wave owns a 64x64 subtile as 4x4 frags of 16x16x32 bf16.
//
// K-loop (T3/T4 minimum 2-phase, counted vmcnt):
//   stage(buf^1, kt+1): 8x global_load_lds dwordx4 per thread (fp32 tiles)
//   s_waitcnt vmcnt(8)   <- kt's loads landed; kt+1's 8 stay IN FLIGHT
//   s_barrier
//   read fp32 frags from LDS (XOR-swizzled), accumulate norms, cvt->bf16, MFMA
//   s_barrier            <- reads of buf done before next overwrite
// In-flight bytes/CU = 2 blocks x 32 KB >> 9.2 KB Little's-law need for HBM.
//
// Swizzle involution: within each row (32 floats = 8 groups of 16 B),
// lds group g' holds global group g'^ (row&7). Staged chunks are 8-row
// aligned, so lane l of a chunk reads global group (l&7)^(l>>3) of row
// (l>>3) -- each 8-lane cluster still covers one contiguous 128 B segment.
__global__ __launch_bounds__(256, 2) void gemm_dist_kernel(
        const float* __restrict__ X, const float* __restrict__ Y,
        float* __restrict__ dist) {
    // XCD-aware swizzle (T1): 1024 % 8 == 0 -> simple form is bijective.
    const int obid = blockIdx.x;
    const int bid  = (obid & 7) * (B_ * 4 / 8) + (obid >> 3);
    const int b  = bid >> 2;
    const int ti = (bid >> 1) & 1;
    const int tj = bid & 1;

    __shared__ float Asf[2][128][32];   // 32 KB (fp32 tile, double-buffered)
    __shared__ float Bsf[2][128][32];   // 32 KB -> 64 KB total = 2 blocks/CU

    const int t    = threadIdx.x;
    const int wave = t >> 6;
    const int lane = t & 63;
    const int wi   = (wave >> 1) << 6;
    const int wj   = (wave & 1) << 6;
    const int fq   = lane >> 4;       // k-quad 0..3
    const int fr   = lane & 15;
    const int sA   = fr & 7;          // read-side swizzle key (= row&7 of frag row)

    // staging geometry: wave w stages chunks 4w..4w+3 (8 rows x 32 floats each)
    const int lr  = lane >> 3;              // row within chunk 0..7
    const int lg  = lane & 7;               // 16B group within row
    const int gsw = (lg ^ lr) << 2;         // swizzled float offset in source row

    const float* gA[4];
    const float* gB[4];
#pragma unroll
    for (int i = 0; i < 4; ++i) {
        const int c = wave * 4 + i;
        gA[i] = X + ((size_t)(b * N_ + ti * 128 + c * 8 + lr)) * D_ + gsw;
        gB[i] = Y + ((size_t)(b * M_ + tj * 128 + c * 8 + lr)) * D_ + gsw;
    }

    f32x4 acc[4][4];
    const f32x4 zero = {0.f, 0.f, 0.f, 0.f};
#pragma unroll
    for (int r = 0; r < 4; ++r)
#pragma unroll
        for (int c = 0; c < 4; ++c) acc[r][c] = zero;

    float nAr[4] = {0.f, 0.f, 0.f, 0.f};   // per-frag-row norm partials
    float nBr[4] = {0.f, 0.f, 0.f, 0.f};

    // lo group holds source floats fq*8..+3, hi group fq*8+4..+7 (order
    // preserved inside each 16B group; only group position is XORed).
    const int g0f = (((fq << 1) | 0) ^ sA) << 2;   // float offset of lo group
    const int g1f = (((fq << 1) | 1) ^ sA) << 2;   // float offset of hi group

    auto stage = [&](int buf, int kt) {
#pragma unroll
        for (int i = 0; i < 4; ++i) {
            const int c = wave * 4 + i;
            GLL16(gA[i] + kt * 32, &Asf[buf][c * 8][0]);
            GLL16(gB[i] + kt * 32, &Bsf[buf][c * 8][0]);
        }
    };

    stage(0, 0);
    for (int kt = 0; kt < D_ / 32; ++kt) {
        const int buf = kt & 1;
        if (kt + 1 < D_ / 32) {
            stage(buf ^ 1, kt + 1);                       // 8 more in flight
            asm volatile("s_waitcnt vmcnt(8)" ::: "memory");  // kt's 8 landed
        } else {
            asm volatile("s_waitcnt vmcnt(0)" ::: "memory");  // drain tail
        }
        __builtin_amdgcn_s_barrier();
        asm volatile("" ::: "memory");

        const float (*Ab)[32] = Asf[buf];
        const float (*Bb)[32] = Bsf[buf];

        bf16x8 af[4], bfv[4];
#pragma unroll
        for (int r = 0; r < 4; ++r) {
            const float* rp = &Ab[wi + r * 16 + fr][0];
            const f32x4 lo = *(const f32x4*)(rp + g0f);
            const f32x4 hi = *(const f32x4*)(rp + g1f);
            if (wj == 0) {   // waves 0,2 cover all 128 A rows exactly once
                nAr[r] += lo[0]*lo[0] + lo[1]*lo[1] + lo[2]*lo[2] + lo[3]*lo[3]
                        + hi[0]*hi[0] + hi[1]*hi[1] + hi[2]*hi[2] + hi[3]*hi[3];
            }
            bf16x8 v;
            v[0]=f2bf(lo[0]); v[1]=f2bf(lo[1]); v[2]=f2bf(lo[2]); v[3]=f2bf(lo[3]);
            v[4]=f2bf(hi[0]); v[5]=f2bf(hi[1]); v[6]=f2bf(hi[2]); v[7]=f2bf(hi[3]);
            af[r] = v;
        }
#pragma unroll
        for (int c = 0; c < 4; ++c) {
            const float* rp = &Bb[wj + c * 16 + fr][0];
            const f32x4 lo = *(const f32x4*)(rp + g0f);
            const f32x4 hi = *(const f32x4*)(rp + g1f);
            if (wi == 0) {   // waves 0,1 cover all 128 B rows exactly once
                nBr[c] += lo[0]*lo[0] + lo[1]*lo[1] + lo[2]*lo[2] + lo[3]*lo[3]
                        + hi[0]*hi[0] + hi[1]*hi[1] + hi[2]*hi[2] + hi[3]*hi[3];
            }
            bf16x8 v;
            v[0]=f2bf(lo[0]); v[1]=f2bf(lo[1]); v[2]=f2bf(lo[2]); v[3]=f2bf(lo[3]);
            v[4]=f2bf(hi[0]); v[5]=f2bf(hi[1]); v[6]=f2bf(hi[2]); v[7]=f2bf(hi[3]);
            bfv[c] = v;
        }

#pragma unroll
        for (int r = 0; r < 4; ++r)
#pragma unroll
            for (int c = 0; c < 4; ++c)
                acc[r][c] = __builtin_amdgcn_mfma_f32_16x16x32_bf16(
                    af[r], bfv[c], acc[r][c], 0, 0, 0);

        asm volatile("" ::: "memory");
        __builtin_amdgcn_s_barrier();
    }

    // Norm reduction: lane's partial covers cols fq*8..+7 of its frag rows;
    // sum across the 4 fq groups (lane bits 4,5), then overlay into dead LDS.
    __syncthreads();
    float* rnx = (float*)&Asf[0][0][0];
    float* rny = rnx + 128;
    if (wj == 0) {
#pragma unroll
        for (int r = 0; r < 4; ++r) {
            float s = nAr[r];
            s += __shfl_xor(s, 16);
            s += __shfl_xor(s, 32);
            if (fq == 0) rnx[wi + r * 16 + fr] = 1.0f / fmaxf(sqrtf(s), 1e-12f);
        }
    }
    if (wi == 0) {
#pragma unroll
        for (int c = 0; c < 4; ++c) {
            float s = nBr[c];
            s += __shfl_xor(s, 16);
            s += __shfl_xor(s, 32);
            if (fq == 0) rny[wj + c * 16 + fr] = 1.0f / fmaxf(sqrtf(s), 1e-12f);
        }
    }
    __syncthreads();

    // Epilogue: C/D layout col=lane&15, row=quad*4+reg (m89-verified).
    float* Dp = dist + (((size_t)b * N_ + ti * 128) * M_) + tj * 128;
#pragma unroll
    for (int r = 0; r < 4; ++r) {
#pragma unroll
        for (int c = 0; c < 4; ++c) {
            const int col = wj + c * 16 + fr;
            const float rc = rny[col];
#pragma unroll
            for (int g = 0; g < 4; ++g) {
                const int rw = wi + r * 16 + fq * 4 + g;
                float v = acc[r][c][g] * rnx[rw] * rc;
                v = fminf(1.0f, fmaxf(-1.0f, v));
                Dp[(size_t)rw * M_ + col] = 1.0f - v;
            }
        }
    }
}

// Phase 2: banded DTW, one wave per batch. Lane l owns columns 4l..4l+3.
// Row recurrence a[j] = min(bt[j], a[j-1]+st[j]) solved as a min-plus scan:
// within-lane fold of (s,t) pairs + 6-step shfl_up wave scan. No barriers.
// (Unchanged this round — isolate the GEMM sync-structure edit.)
__global__ __launch_bounds__(64) void dtw_kernel(
        const float* __restrict__ dist, float* __restrict__ out) {
    const int b = blockIdx.x;
    const int lane = threadIdx.x;
    const float* Db = dist + (size_t)b * N_ * M_;
    const int j0 = lane << 2;

    // ---- row 0: masked cumulative sum ----
    float4 d = *(const float4*)(Db + j0);
    float s0 = d.x, s1 = s0 + d.y, s2 = s1 + d.z, s3 = s2 + d.w;
    float tot = s3;
#pragma unroll
    for (int off = 1; off < 64; off <<= 1) {
        float o = __shfl_up(tot, off);
        if (lane >= off) tot += o;
    }
    float excl = __shfl_up(tot, 1);
    if (lane == 0) excl = 0.f;
    float prev[4];
    prev[0] = (j0 + 0 <= RAD) ? excl + s0 : BIGF;
    prev[1] = (j0 + 1 <= RAD) ? excl + s1 : BIGF;
    prev[2] = (j0 + 2 <= RAD) ? excl + s2 : BIGF;
    prev[3] = (j0 + 3 <= RAD) ? excl + s3 : BIGF;

    float4 dn = *(const float4*)(Db + M_ + j0);  // prefetch row 1

    for (int i = 1; i < N_; ++i) {
        d = dn;
        if (i + 1 < N_) dn = *(const float4*)(Db + (size_t)(i + 1) * M_ + j0);

        const float pm1 = __shfl_up(prev[3], 1);        // prev[j-1] at slot 0
        const float p00 = __shfl(prev[0], 0);
        const float d00 = __shfl(d.x, 0);
        const float a0 = (i <= RAD) ? p00 + d00 : BIGF;

        const float de[4] = {d.x, d.y, d.z, d.w};
        const float ps[4] = {pm1, prev[0], prev[1], prev[2]};

        // within-lane inclusive fold of (st, bt) pairs; element j==0 is the
        // monoid identity (0, +BIG)
        float S = 0.f, T = BIGF;
        float Se[4], Te[4];
#pragma unroll
        for (int e = 0; e < 4; ++e) {
            const int j = j0 + e;
            float st, bt;
            if (j == 0) {
                st = 0.f; bt = BIGF;
            } else {
                const bool in = (j >= i - RAD) && (j <= i + RAD);
                const float c = fminf(prev[e], ps[e]);
                bt = in ? c + de[e] : BIGF;
                st = in ? de[e] : BIGF;
            }
            T = fminf(bt, T + st);   // comb(p, x)
            S = S + st;
            Se[e] = S; Te[e] = T;
        }

        // wave inclusive scan of lane totals with comb(left, self)
        float iS = S, iT = T;
#pragma unroll
        for (int off = 1; off < 64; off <<= 1) {
            float oS = __shfl_up(iS, off);
            float oT = __shfl_up(iT, off);
            if (lane >= off) {
                iT = fminf(iT, oT + iS);
                iS = oS + iS;
            }
        }
        float eS = __shfl_up(iS, 1);
        float eT = __shfl_up(iT, 1);
        if (lane == 0) { eS = 0.f; eT = BIGF; }

#pragma unroll
        for (int e = 0; e < 4; ++e) {
            const float fS = eS + Se[e];
            const float fT = fminf(Te[e], eT + Se[e]);
            prev[e] = fminf(fT, a0 + fS);
        }
        if (lane == 0) prev[0] = a0;
    }

    if (lane == 63) out[b] = prev[3];
}

extern "C" void kernel_launch(void* const* d_in, const int* in_sizes, int n_in,
                              void* d_out, int out_size, void* d_ws, size_t ws_size,
                              hipStream_t stream) {
    const float* seq1 = (const float*)d_in[0];
    const float* seq2 = (const float*)d_in[1];
    float* out = (float*)d_out;
    float* dist = (float*)d_ws;   // 256*256*256*4 = 64 MiB scratch

    hipLaunchKernelGGL(gemm_dist_kernel, dim3(B_ * 4), dim3(256), 0, stream,
                       seq1, seq2, dist);
    hipLaunchKernelGGL(dtw_kernel, dim3(B_), dim3(64), 0, stream, dist, out);
}